// Round 2
// baseline (352.954 us; speedup 1.0000x reference)
//
#include <hip/hip_runtime.h>

#define BATCH 512
#define V 6890
#define NJ 24
#define VH (V/2)   // 3445 float2 per feature row

#define SD_N (V*30)
#define VT_N (V*3)
#define W_N  (V*24)
#define TOT_PK (SD_N+VT_N+W_N)          // 392730 floats
#define PREP_BLOCKS ((TOT_PK+255)/256)  // 1535
#define NCH 8
#define JREG_BLOCKS (NJ*NCH)            // 192
#define CH_SZ ((V+NCH-1)/NCH)           // 862

// workspace layout (float indices)
#define JT_OFF  155648     // 72  = Jr @ v_template
#define JS_OFF  155720     // 720 = Jr @ shapedirs   (contiguous after JT: 792 total)
#define PK_OFF  156672     // transposed fp32, rows stride V:
                           //   sd row j at j*V; vt row k at (30+k)*V; W row n at (33+n)*V

__device__ const int d_par[NJ] = {-1,0,0,0,1,2,3,4,5,6,7,8,9,9,9,12,13,14,16,17,18,19,20,21};
// tree depth of each joint (max 8) -> level-parallel chain
__device__ const int d_dep[NJ] = {0,1,1,1,2,2,2,3,3,3,4,4,4,4,4,5,5,5,6,6,7,7,8,8};

// ---------------- fused: transpose + chunked joint-regressor (atomic partials) -------
// blocks [0, PREP_BLOCKS): transpose to [feature][V] fp32
// blocks [PREP_BLOCKS, +192): (joint j, chunk ch) partial reduction -> atomicAdd
__global__ __launch_bounds__(256) void prepjreg_k(
    const float* __restrict__ sd, const float* __restrict__ vt, const float* __restrict__ W,
    const float* __restrict__ Jr,
    float* __restrict__ dst, float* __restrict__ JTo, float* __restrict__ JSo)
{
  __shared__ float red[4*33];
  const int bid = blockIdx.x;
  const int t = threadIdx.x;
  if (bid < PREP_BLOCKS){
    int i = bid*256 + t;
    if (i >= TOT_PK) return;
    float val;
    if (i < SD_N){ int j=i/V, v=i-j*V; val = sd[v*30+j]; }
    else if (i < SD_N+VT_N){ int o=i-SD_N; int j=o/V, v=o-j*V; val = vt[v*3+j]; }
    else { int o=i-SD_N-VT_N; int j=o/V, v=o-j*V; val = W[v*24+j]; }
    dst[i] = val;
    return;
  }
  const int r  = bid - PREP_BLOCKS;
  const int j  = r % NJ;
  const int ch = r / NJ;
  const int v0 = ch*CH_SZ;
  const int v1 = (v0+CH_SZ < V) ? v0+CH_SZ : V;
  float acc[33];
#pragma unroll
  for (int m=0;m<33;m++) acc[m]=0.f;
  for (int v=v0+t; v<v1; v+=256){
    const float jr = Jr[j*V+v];
    const float* __restrict__ vp = vt + v*3;
    acc[0] = fmaf(jr, vp[0], acc[0]);
    acc[1] = fmaf(jr, vp[1], acc[1]);
    acc[2] = fmaf(jr, vp[2], acc[2]);
    const float2* __restrict__ sp = (const float2*)(sd + v*30);  // 120B stride, 8B aligned
#pragma unroll
    for (int m=0;m<15;m++){
      const float2 s = sp[m];
      acc[3+2*m]   = fmaf(jr, s.x, acc[3+2*m]);
      acc[3+2*m+1] = fmaf(jr, s.y, acc[3+2*m+1]);
    }
  }
  const int lane = t & 63, wid = t >> 6;
#pragma unroll
  for (int m=0;m<33;m++){
    float x = acc[m];
    x += __shfl_xor(x, 1);
    x += __shfl_xor(x, 2);
    x += __shfl_xor(x, 4);
    x += __shfl_xor(x, 8);
    x += __shfl_xor(x, 16);
    x += __shfl_xor(x, 32);
    if (lane == 0) red[wid*33+m] = x;
  }
  __syncthreads();
  if (t < 33){
    const float s = red[t] + red[33+t] + red[66+t] + red[99+t];
    if (t < 3) atomicAdd(&JTo[j*3+t], s);
    else       atomicAdd(&JSo[j*30 + (t-3)], s);   // JS[(j*3+k)*10+l] = j*30+k*10+l
  }
}

// ---------------- fused batch-prep + LBS ---------------------------------------------
// grid (14, 256). Wave 0 computes the 2 batches' skinning matrices (lane j = joint j,
// lanes 32..55 = batch 1) via register rodrigues + level-parallel shfl chain -> LDS.
// Waves 1-3 overlap the shapedirs blend. One barrier, then the n-loop reads A from LDS.
__global__ __launch_bounds__(256, 8) void fused_k(
    const float* __restrict__ betas, const float* __restrict__ body_pose,
    const float* __restrict__ go, const float* __restrict__ transl,
    const float* __restrict__ JT, const float* __restrict__ JS,
    const float2* __restrict__ pk, float* __restrict__ out, float* __restrict__ jout)
{
  const int t = threadIdx.x;
  const int vh = blockIdx.x*256 + t;
  const bool valid = (vh < VH);
  const int bg = blockIdx.y;
  __shared__ float lA[NJ*24];   // [n][q][12] : n*24 + q*12 + k   (16B-aligned rows)

  // ---- block-uniform per-batch scalars (compiler scalarizes -> s_load) ----
  float b0s[2], cf[2][10], tr[2][3];
#pragma unroll
  for (int q=0;q<2;q++){
    const float* __restrict__ bp = betas + (bg*2+q)*11;
    const float bb0 = bp[0];
    b0s[q] = bb0;
#pragma unroll
    for (int l=0;l<10;l++) cf[q][l] = bb0*bp[1+l];
    const float* __restrict__ tp = transl + (bg*2+q)*3;
    tr[q][0]=tp[0]; tr[q][1]=tp[1]; tr[q][2]=tp[2];
  }

  // ---- wave-0 prologue: skinning matrices for both batches ----
  if (t < 56){
    const int q = t >> 5, j = t & 31;
    if (j < NJ){
      const int b = bg*2 + q;
      // betas (per-lane; 2 distinct addresses per wave -> L1 broadcast)
      const float* __restrict__ bp = betas + b*11;
      float be[11];
#pragma unroll
      for (int i=0;i<11;i++) be[i] = bp[i];
      // rest joint position lJ = b0*(JT + JS.beta)
      float Jv[3];
#pragma unroll
      for (int k=0;k<3;k++){
        float s = JT[j*3+k];
#pragma unroll
        for (int l=0;l<10;l++) s = fmaf(be[1+l], JS[j*30 + k*10 + l], s);
        Jv[k] = be[0]*s;
      }
      // rodrigues
      float p0,p1,p2;
      if (j==0){ p0=go[b*3+0]; p1=go[b*3+1]; p2=go[b*3+2]; }
      else { int o=b*69+(j-1)*3; p0=body_pose[o]; p1=body_pose[o+1]; p2=body_pose[o+2]; }
      float a0=p0+1e-8f, a1=p1+1e-8f, a2=p2+1e-8f;
      float angle = sqrtf(a0*a0+a1*a1+a2*a2);
      float inv = 1.0f/angle;
      float rx=p0*inv, ry=p1*inv, rz=p2*inv;
      float sn = sinf(angle), cs = cosf(angle), mc = 1.0f-cs;
      float K[9] = {0.f,-rz,ry, rz,0.f,-rx, -ry,rx,0.f};
      float KK[9];
#pragma unroll
      for (int rr=0;rr<3;rr++)
#pragma unroll
        for (int cc=0;cc<3;cc++)
          KK[rr*3+cc] = K[rr*3+0]*K[0+cc] + K[rr*3+1]*K[3+cc] + K[rr*3+2]*K[6+cc];
      float R[9];
#pragma unroll
      for (int e=0;e<9;e++){
        float ident = (e==0||e==4||e==8)?1.0f:0.0f;
        R[e] = ident + sn*K[e] + mc*KK[e];
      }
      // local transform L (3x4): rel translation needs parent's rest pos
      const int par = d_par[j];
      const int dep = d_dep[j];
      const int parlane = ((j==0)?0:par) + (q<<5);
      const float Jp0 = __shfl(Jv[0], parlane);
      const float Jp1 = __shfl(Jv[1], parlane);
      const float Jp2 = __shfl(Jv[2], parlane);
      float l[12];
      l[0]=R[0]; l[1]=R[1]; l[2]=R[2];  l[3]  = (j==0)? Jv[0] : Jv[0]-Jp0;
      l[4]=R[3]; l[5]=R[4]; l[6]=R[5];  l[7]  = (j==0)? Jv[1] : Jv[1]-Jp1;
      l[8]=R[6]; l[9]=R[7]; l[10]=R[8]; l[11] = (j==0)? Jv[2] : Jv[2]-Jp2;
      // level-parallel chain: 8 levels of W_j = W_par * L_j
      float w[12];
#pragma unroll
      for (int k=0;k<12;k++) w[k] = l[k];
#pragma unroll
      for (int d=1; d<=8; d++){
        float wp[12];
#pragma unroll
        for (int k=0;k<12;k++) wp[k] = __shfl(w[k], parlane);
        float c[12];
#pragma unroll
        for (int rr=0;rr<3;rr++){
#pragma unroll
          for (int cc=0;cc<4;cc++){
            float s = wp[rr*4+0]*l[0*4+cc] + wp[rr*4+1]*l[1*4+cc] + wp[rr*4+2]*l[2*4+cc];
            if (cc==3) s += wp[rr*4+3];
            c[rr*4+cc] = s;
          }
        }
        const bool sel = (dep == d);
#pragma unroll
        for (int k=0;k<12;k++) w[k] = sel ? c[k] : w[k];
      }
      // J_transformed (pre-adjust translation) -- one block column writes it
      if (blockIdx.x == 0){
        float* __restrict__ jo = jout + b*72 + j*3;
        jo[0]=w[3]; jo[1]=w[7]; jo[2]=w[11];
      }
      // A: t-col -= R_world @ J_rest
      w[3]  -= w[0]*Jv[0] + w[1]*Jv[1] + w[2]*Jv[2];
      w[7]  -= w[4]*Jv[0] + w[5]*Jv[1] + w[6]*Jv[2];
      w[11] -= w[8]*Jv[0] + w[9]*Jv[1] + w[10]*Jv[2];
      const int base = j*24 + q*12;
      *(float4*)&lA[base+0] = make_float4(w[0],w[1],w[2],w[3]);
      *(float4*)&lA[base+4] = make_float4(w[4],w[5],w[6],w[7]);
      *(float4*)&lA[base+8] = make_float4(w[8],w[9],w[10],w[11]);
    }
  }

  // ---- shapedirs blend (overlaps wave-0 prologue) ----
  float2 vs[2][3];
  if (valid){
    const float2 vt0 = pk[30*VH + vh];
    const float2 vt1 = pk[31*VH + vh];
    const float2 vt2 = pk[32*VH + vh];
#pragma unroll
    for (int q=0;q<2;q++){
      const float b0 = b0s[q];
      vs[q][0] = make_float2(b0*vt0.x, b0*vt0.y);
      vs[q][1] = make_float2(b0*vt1.x, b0*vt1.y);
      vs[q][2] = make_float2(b0*vt2.x, b0*vt2.y);
    }
#pragma unroll
    for (int l=0;l<10;l++){
      const float2 s0 = pk[(0*10+l)*VH + vh];
      const float2 s1 = pk[(1*10+l)*VH + vh];
      const float2 s2 = pk[(2*10+l)*VH + vh];
#pragma unroll
      for (int q=0;q<2;q++){
        const float c = cf[q][l];
        vs[q][0].x = fmaf(c, s0.x, vs[q][0].x); vs[q][0].y = fmaf(c, s0.y, vs[q][0].y);
        vs[q][1].x = fmaf(c, s1.x, vs[q][1].x); vs[q][1].y = fmaf(c, s1.y, vs[q][1].y);
        vs[q][2].x = fmaf(c, s2.x, vs[q][2].x); vs[q][2].y = fmaf(c, s2.y, vs[q][2].y);
      }
    }
  }

  __syncthreads();

  if (!valid) return;

  float y[2][6];
#pragma unroll
  for (int q=0;q<2;q++)
#pragma unroll
    for (int i=0;i<6;i++) y[q][i] = 0.f;

#pragma unroll 4
  for (int n=0;n<NJ;n++){
    const float2 w = pk[(33+n)*VH + vh];
#pragma unroll
    for (int q=0;q<2;q++){
      const float4 A0 = *(const float4*)&lA[n*24+q*12+0];   // uniform -> broadcast
      const float4 A1 = *(const float4*)&lA[n*24+q*12+4];
      const float4 A2 = *(const float4*)&lA[n*24+q*12+8];
      float tt;
      tt = fmaf(A0.z, vs[q][2].x, fmaf(A0.y, vs[q][1].x, fmaf(A0.x, vs[q][0].x, A0.w)));
      y[q][0] = fmaf(w.x, tt, y[q][0]);
      tt = fmaf(A0.z, vs[q][2].y, fmaf(A0.y, vs[q][1].y, fmaf(A0.x, vs[q][0].y, A0.w)));
      y[q][1] = fmaf(w.y, tt, y[q][1]);
      tt = fmaf(A1.z, vs[q][2].x, fmaf(A1.y, vs[q][1].x, fmaf(A1.x, vs[q][0].x, A1.w)));
      y[q][2] = fmaf(w.x, tt, y[q][2]);
      tt = fmaf(A1.z, vs[q][2].y, fmaf(A1.y, vs[q][1].y, fmaf(A1.x, vs[q][0].y, A1.w)));
      y[q][3] = fmaf(w.y, tt, y[q][3]);
      tt = fmaf(A2.z, vs[q][2].x, fmaf(A2.y, vs[q][1].x, fmaf(A2.x, vs[q][0].x, A2.w)));
      y[q][4] = fmaf(w.x, tt, y[q][4]);
      tt = fmaf(A2.z, vs[q][2].y, fmaf(A2.y, vs[q][1].y, fmaf(A2.x, vs[q][0].y, A2.w)));
      y[q][5] = fmaf(w.y, tt, y[q][5]);
    }
  }

  const int v0 = 2*vh;
#pragma unroll
  for (int q=0;q<2;q++){
    const float t0 = tr[q][0], t1 = tr[q][1], t2 = tr[q][2];
    const int b = bg*2 + q;
    float2* __restrict__ o2 = (float2*)(out + (b*V + v0)*3);
    o2[0] = make_float2(y[q][0]+t0, y[q][2]+t1);
    o2[1] = make_float2(y[q][4]+t2, y[q][1]+t0);
    o2[2] = make_float2(y[q][3]+t1, y[q][5]+t2);
  }
}

extern "C" void kernel_launch(void* const* d_in, const int* in_sizes, int n_in,
                              void* d_out, int out_size, void* d_ws, size_t ws_size,
                              hipStream_t stream)
{
  const float* betas     = (const float*)d_in[0];
  const float* body_pose = (const float*)d_in[1];
  const float* go        = (const float*)d_in[2];
  const float* transl    = (const float*)d_in[3];
  const float* sdirs     = (const float*)d_in[4];
  const float* vtempl    = (const float*)d_in[5];
  const float* Jr        = (const float*)d_in[6];
  const float* lw        = (const float*)d_in[7];
  float* wsf = (float*)d_ws;
  float* out = (float*)d_out;

  // zero JT+JS (792 floats) for the atomic partial reduction
  hipMemsetAsync((void*)(wsf+JT_OFF), 0, 792*sizeof(float), stream);
  hipLaunchKernelGGL(prepjreg_k, dim3(PREP_BLOCKS + JREG_BLOCKS), dim3(256), 0, stream,
                     sdirs, vtempl, lw, Jr, wsf+PK_OFF, wsf+JT_OFF, wsf+JS_OFF);
  hipLaunchKernelGGL(fused_k, dim3((VH+255)/256, BATCH/2), dim3(256), 0, stream,
                     betas, body_pose, go, transl, wsf+JT_OFF, wsf+JS_OFF,
                     (const float2*)(wsf+PK_OFF), out, out + BATCH*V*3);
}

// Round 3
// 144.288 us; speedup vs baseline: 2.4462x; 2.4462x over previous
//
#include <hip/hip_runtime.h>

#define BATCH 512
#define V 6890
#define NJ 24
#define VH (V/2)   // 3445 float2 per feature row

#define SD_N (V*30)
#define VT_N (V*3)
#define W_N  (V*24)
#define TOT_PK (SD_N+VT_N+W_N)          // 392730 floats
#define PREP_BLOCKS ((TOT_PK+255)/256)  // 1535
#define NCH 8
#define JREG_BLOCKS (NJ*NCH)            // 192
#define CH_SZ ((V+NCH-1)/NCH)           // 862

// workspace layout (float indices)
// A layout: 256 groups of 2 batches: off = (b>>1)*576 + n*24 + (b&1)*12 + rc
#define A_OFF   0          // BATCH*288 fp32 skinning matrices (pair-grouped)
#define BS_OFF  147456     // BATCH*16 per-batch scalars {b0, b0*beta[1..10], transl[0..2], pad}
#define JP_OFF  155648     // 192*33 jreg partials: [(ch*NJ+j)*33 + m]
#define PK_OFF  162048     // transposed fp32, rows stride V:
                           //   sd row f at f*V; vt row k at (30+k)*V; W row n at (33+n)*V

__device__ const int d_par[NJ] = {-1,0,0,0,1,2,3,4,5,6,7,8,9,9,9,12,13,14,16,17,18,19,20,21};

// ---------------- fused: transpose + chunked joint-regressor (partials) --------------
// blocks [0, PREP_BLOCKS): transpose to [feature][V] fp32
// blocks [PREP_BLOCKS, +192): (joint j, chunk ch) partial reduction -> JP (no atomics)
__global__ __launch_bounds__(256) void prepjreg_k(
    const float* __restrict__ sd, const float* __restrict__ vt, const float* __restrict__ W,
    const float* __restrict__ Jr,
    float* __restrict__ dst, float* __restrict__ JP)
{
  __shared__ float red[4*33];
  const int bid = blockIdx.x;
  const int t = threadIdx.x;
  if (bid < PREP_BLOCKS){
    int i = bid*256 + t;
    if (i >= TOT_PK) return;
    float val;
    if (i < SD_N){ int j=i/V, v=i-j*V; val = sd[v*30+j]; }
    else if (i < SD_N+VT_N){ int o=i-SD_N; int j=o/V, v=o-j*V; val = vt[v*3+j]; }
    else { int o=i-SD_N-VT_N; int j=o/V, v=o-j*V; val = W[v*24+j]; }
    dst[i] = val;
    return;
  }
  const int r  = bid - PREP_BLOCKS;   // r = ch*NJ + j
  const int j  = r % NJ;
  const int v0 = (r / NJ)*CH_SZ;
  const int v1 = (v0+CH_SZ < V) ? v0+CH_SZ : V;
  float acc[33];
#pragma unroll
  for (int m=0;m<33;m++) acc[m]=0.f;
  for (int v=v0+t; v<v1; v+=256){
    const float jr = Jr[j*V+v];
    const float* __restrict__ vp = vt + v*3;
    acc[0] = fmaf(jr, vp[0], acc[0]);
    acc[1] = fmaf(jr, vp[1], acc[1]);
    acc[2] = fmaf(jr, vp[2], acc[2]);
    const float2* __restrict__ sp = (const float2*)(sd + v*30);  // 120B stride, 8B aligned
#pragma unroll
    for (int m=0;m<15;m++){
      const float2 s = sp[m];
      acc[3+2*m]   = fmaf(jr, s.x, acc[3+2*m]);
      acc[3+2*m+1] = fmaf(jr, s.y, acc[3+2*m+1]);
    }
  }
  const int lane = t & 63, wid = t >> 6;
#pragma unroll
  for (int m=0;m<33;m++){
    float x = acc[m];
    x += __shfl_xor(x, 1);
    x += __shfl_xor(x, 2);
    x += __shfl_xor(x, 4);
    x += __shfl_xor(x, 8);
    x += __shfl_xor(x, 16);
    x += __shfl_xor(x, 32);
    if (lane == 0) red[wid*33+m] = x;
  }
  __syncthreads();
  if (t < 33){
    JP[r*33 + t] = red[t] + red[33+t] + red[66+t] + red[99+t];
    // m<3: Jr@vt col m ; m>=3: Jr@sd feature (m-3), feature f = k*10+l
  }
}

// ---------------- per-batch: joints, rodrigues, chain, A (pair-grouped), J_out -------
__global__ __launch_bounds__(64) void batch_k(
    const float* __restrict__ betas, const float* __restrict__ body_pose,
    const float* __restrict__ go, const float* __restrict__ transl,
    const float* __restrict__ JP,
    float* __restrict__ A, float* __restrict__ bsc, float* __restrict__ jout)
{
  const int b = blockIdx.x;
  const int t = threadIdx.x;
  __shared__ float lb[11];
  __shared__ float lJ[72];
  __shared__ float lR[NJ*9];
  __shared__ float lL[NJ*12];
  __shared__ float lW[NJ*12];
  if (t < 11) lb[t] = betas[b*11+t];
  __syncthreads();
  const float b0 = lb[0];
  for (int idx=t; idx<72; idx+=64){
    const int j = idx/3, k = idx-3*j;
    float s = 0.f;
#pragma unroll
    for (int ch=0; ch<NCH; ch++){
      const float* __restrict__ jp = JP + (ch*NJ+j)*33;
      float ss = jp[k];
#pragma unroll
      for (int l=0;l<10;l++) ss = fmaf(lb[1+l], jp[3 + k*10 + l], ss);
      s += ss;
    }
    lJ[idx] = b0*s;
  }
  if (t==0) bsc[b*16] = b0;
  if (t>=1 && t<11) bsc[b*16+t] = b0*lb[t];
  if (t<3) bsc[b*16+11+t] = transl[b*3+t];
  if (t < NJ){
    float p0,p1,p2;
    if (t==0){ p0=go[b*3+0]; p1=go[b*3+1]; p2=go[b*3+2]; }
    else { int o=b*69+(t-1)*3; p0=body_pose[o]; p1=body_pose[o+1]; p2=body_pose[o+2]; }
    float a0=p0+1e-8f, a1=p1+1e-8f, a2=p2+1e-8f;
    float angle = sqrtf(a0*a0+a1*a1+a2*a2);
    float inv = 1.0f/angle;
    float rx=p0*inv, ry=p1*inv, rz=p2*inv;
    float sn = sinf(angle), cs = cosf(angle), mc = 1.0f-cs;
    float K[9] = {0.f,-rz,ry, rz,0.f,-rx, -ry,rx,0.f};
    float KK[9];
    #pragma unroll
    for (int r=0;r<3;r++)
      #pragma unroll
      for (int c=0;c<3;c++)
        KK[r*3+c] = K[r*3+0]*K[0+c] + K[r*3+1]*K[3+c] + K[r*3+2]*K[6+c];
    #pragma unroll
    for (int e=0;e<9;e++){
      float ident = (e==0||e==4||e==8)?1.0f:0.0f;
      lR[t*9+e] = ident + sn*K[e] + mc*KK[e];
    }
  }
  __syncthreads();
  for (int idx=t; idx<288; idx+=64){
    int j = idx/12, rc = idx-12*j, r = rc>>2, c = rc&3;
    float val;
    if (c<3) val = lR[j*9 + r*3 + c];
    else {
      int p = (j==0) ? 0 : d_par[j];
      val = (j==0) ? lJ[r] : (lJ[j*3+r] - lJ[p*3+r]);
    }
    lL[idx] = val;
  }
  __syncthreads();
  if (t<12) lW[t] = lL[t];
  __syncthreads();
  for (int i=1;i<NJ;i++){
    if (t<12){
      int p = d_par[i];
      int r = t>>2, c = t&3;
      float s = lW[p*12+r*4+0]*lL[i*12+0+c]
              + lW[p*12+r*4+1]*lL[i*12+4+c]
              + lW[p*12+r*4+2]*lL[i*12+8+c];
      if (c==3) s += lW[p*12+r*4+3];
      lW[i*12+t] = s;
    }
    __syncthreads();
  }
  for (int idx=t; idx<72; idx+=64){
    int j=idx/3, k=idx-3*j;
    jout[b*72+idx] = lW[j*12+k*4+3];
  }
  // A (pair-grouped layout) = world with t-col -= R_world @ J
  const int g = b>>1, q = b&1;
  float* __restrict__ Ab = A + g*576 + q*12;
  for (int idx=t; idx<288; idx+=64){
    int n=idx/12, rc=idx-12*n, r=rc>>2, c=rc&3;
    float val = lW[n*12+rc];
    if (c==3){
      val -= lW[n*12+r*4+0]*lJ[n*3+0] + lW[n*12+r*4+1]*lJ[n*3+1] + lW[n*12+r*4+2]*lJ[n*3+2];
    }
    Ab[n*24 + rc] = val;
  }
}

// ---------------- main LBS: 1 vertex-pair x 2 block-shared batches per thread ---------
__global__ __launch_bounds__(256, 8) void main_k(
    const float* __restrict__ A, const float* __restrict__ bsc,
    const float2* __restrict__ pk, float* __restrict__ out)
{
  const int vh = blockIdx.x*256 + threadIdx.x;
  if (vh >= VH) return;
  const int bg = blockIdx.y;                 // batch pair (shared by block)
  const float* __restrict__ Ag = A + bg*576;
  const float* __restrict__ bs = bsc + bg*32;

  const float2 vt0 = pk[30*VH + vh];
  const float2 vt1 = pk[31*VH + vh];
  const float2 vt2 = pk[32*VH + vh];

  float2 vs[2][3];
#pragma unroll
  for (int q=0;q<2;q++){
    const float b0 = bs[q*16];
    vs[q][0] = make_float2(b0*vt0.x, b0*vt0.y);
    vs[q][1] = make_float2(b0*vt1.x, b0*vt1.y);
    vs[q][2] = make_float2(b0*vt2.x, b0*vt2.y);
  }
#pragma unroll
  for (int l=0;l<10;l++){
    const float2 s0 = pk[(0*10+l)*VH + vh];
    const float2 s1 = pk[(1*10+l)*VH + vh];
    const float2 s2 = pk[(2*10+l)*VH + vh];
#pragma unroll
    for (int q=0;q<2;q++){
      const float c = bs[q*16+1+l];
      vs[q][0].x = fmaf(c, s0.x, vs[q][0].x); vs[q][0].y = fmaf(c, s0.y, vs[q][0].y);
      vs[q][1].x = fmaf(c, s1.x, vs[q][1].x); vs[q][1].y = fmaf(c, s1.y, vs[q][1].y);
      vs[q][2].x = fmaf(c, s2.x, vs[q][2].x); vs[q][2].y = fmaf(c, s2.y, vs[q][2].y);
    }
  }

  float y[2][6];
#pragma unroll
  for (int q=0;q<2;q++)
#pragma unroll
    for (int i=0;i<6;i++) y[q][i] = 0.f;

#pragma unroll 4
  for (int n=0;n<NJ;n++){
    const float2 w = pk[(33+n)*VH + vh];
#pragma unroll
    for (int q=0;q<2;q++){
      const float* __restrict__ an = Ag + n*24 + q*12;   // block-uniform -> s_load
      float tt;
      tt = fmaf(an[2], vs[q][2].x, fmaf(an[1], vs[q][1].x, fmaf(an[0], vs[q][0].x, an[3])));
      y[q][0] = fmaf(w.x, tt, y[q][0]);
      tt = fmaf(an[2], vs[q][2].y, fmaf(an[1], vs[q][1].y, fmaf(an[0], vs[q][0].y, an[3])));
      y[q][1] = fmaf(w.y, tt, y[q][1]);
      tt = fmaf(an[6], vs[q][2].x, fmaf(an[5], vs[q][1].x, fmaf(an[4], vs[q][0].x, an[7])));
      y[q][2] = fmaf(w.x, tt, y[q][2]);
      tt = fmaf(an[6], vs[q][2].y, fmaf(an[5], vs[q][1].y, fmaf(an[4], vs[q][0].y, an[7])));
      y[q][3] = fmaf(w.y, tt, y[q][3]);
      tt = fmaf(an[10], vs[q][2].x, fmaf(an[9], vs[q][1].x, fmaf(an[8], vs[q][0].x, an[11])));
      y[q][4] = fmaf(w.x, tt, y[q][4]);
      tt = fmaf(an[10], vs[q][2].y, fmaf(an[9], vs[q][1].y, fmaf(an[8], vs[q][0].y, an[11])));
      y[q][5] = fmaf(w.y, tt, y[q][5]);
    }
  }

  const int v0 = 2*vh;
#pragma unroll
  for (int q=0;q<2;q++){
    const float t0 = bs[q*16+11], t1 = bs[q*16+12], t2 = bs[q*16+13];
    const int b = bg*2 + q;
    float2* __restrict__ o2 = (float2*)(out + (b*V + v0)*3);
    o2[0] = make_float2(y[q][0]+t0, y[q][2]+t1);
    o2[1] = make_float2(y[q][4]+t2, y[q][1]+t0);
    o2[2] = make_float2(y[q][3]+t1, y[q][5]+t2);
  }
}

extern "C" void kernel_launch(void* const* d_in, const int* in_sizes, int n_in,
                              void* d_out, int out_size, void* d_ws, size_t ws_size,
                              hipStream_t stream)
{
  const float* betas     = (const float*)d_in[0];
  const float* body_pose = (const float*)d_in[1];
  const float* go        = (const float*)d_in[2];
  const float* transl    = (const float*)d_in[3];
  const float* sdirs     = (const float*)d_in[4];
  const float* vtempl    = (const float*)d_in[5];
  const float* Jr        = (const float*)d_in[6];
  const float* lw        = (const float*)d_in[7];
  float* wsf = (float*)d_ws;
  float* out = (float*)d_out;

  hipLaunchKernelGGL(prepjreg_k, dim3(PREP_BLOCKS + JREG_BLOCKS), dim3(256), 0, stream,
                     sdirs, vtempl, lw, Jr, wsf+PK_OFF, wsf+JP_OFF);
  hipLaunchKernelGGL(batch_k, dim3(BATCH), dim3(64), 0, stream,
                     betas, body_pose, go, transl, wsf+JP_OFF,
                     wsf+A_OFF, wsf+BS_OFF, out + BATCH*V*3);
  hipLaunchKernelGGL(main_k, dim3((VH+255)/256, BATCH/2), dim3(256), 0, stream,
                     wsf+A_OFF, wsf+BS_OFF, (const float2*)(wsf+PK_OFF), out);
}